// Round 6
// baseline (2574.007 us; speedup 1.0000x reference)
//
#include <hip/hip_runtime.h>
#include <hip/hip_bf16.h>

typedef _Float16 half2_t __attribute__((ext_vector_type(2)));
typedef _Float16 f16x8   __attribute__((ext_vector_type(8)));
typedef float    f32x4   __attribute__((ext_vector_type(4)));
typedef unsigned short u16;
typedef unsigned int   u32;

#define N_NODES 65536
#define IN_DIM  256
#define HIDDEN  256
#define G3      768     // 3*HIDDEN gate rows
#define NGRAPH  128

__device__ __forceinline__ float sigf(float x)    { return 1.f / (1.f + __expf(-x)); }
__device__ __forceinline__ float tanhfast(float x){ return 2.f / (1.f + __expf(-2.f * x)) - 1.f; }

// ---- per-graph starts via binary search on sorted batch (int32/int64 autodetect) ----
__global__ void k_starts(const int* __restrict__ batch, int* __restrict__ starts, int n, int ngraph) {
    int g = blockIdx.x * blockDim.x + threadIdx.x;
    if (g > ngraph) return;
    int stride = (batch[n - 1] == 0) ? 2 : 1;
    if (g == ngraph) { starts[g] = n; return; }
    int lo = 0, hi = n;
    while (lo < hi) { int mid = (lo + hi) >> 1; if (batch[(size_t)mid * stride] < g) lo = mid + 1; else hi = mid; }
    starts[g] = lo;
}

// ---- f32 -> f16 elementwise (n multiple of 8) ----
__global__ void k_cvt8(const float* __restrict__ s, u16* __restrict__ d, int n) {
    int t = blockIdx.x * 256 + threadIdx.x;
    int i = t * 8;
    if (i >= n) return;
    float4 a = ((const float4*)(s + i))[0];
    float4 b = ((const float4*)(s + i))[1];
    f16x8 o;
    o[0] = (_Float16)a.x; o[1] = (_Float16)a.y; o[2] = (_Float16)a.z; o[3] = (_Float16)a.w;
    o[4] = (_Float16)b.x; o[5] = (_Float16)b.y; o[6] = (_Float16)b.z; o[7] = (_Float16)b.w;
    *(f16x8*)(d + i) = o;
}

// ---- W_hh f32 [768][256] -> swizzled f16 chunks for k_rec's 256-thread/3-row
// layout. t = ((w*3 + rg)*32 + i)*64 + l  (w=wave 0..3, rg=row-group 0..2,
// i=k-chunk 0..31, l=lane 0..63) holds W_hh[row = rg*256 + w*64 + l][8i..8i+7].
__global__ void k_swz(const float* __restrict__ W, uint4* __restrict__ out) {
    int t = blockIdx.x * 256 + threadIdx.x;
    if (t >= 24576) return;
    int l = t & 63, i = (t >> 6) & 31, rest = t >> 11;  // rest = w*3+rg, 0..11
    int w = rest / 3, rg = rest % 3;
    int row = rg * 256 + w * 64 + l, col = i * 8;
    const float* s = W + row * 256 + col;
    f16x8 o;
#pragma unroll
    for (int q = 0; q < 8; q++) o[q] = (_Float16)s[q];
    out[t] = __builtin_bit_cast(uint4, o);
}

// ---- GEMM: C[M][N] f16 = A[M][K] * B[N][K]^T + bias[N]
// A is f32 (converted during LDS staging) or f16. 128x128 tile per 256-thread
// WG, 4 waves each 64x64 (4x4 of 16x16x32 f16 MFMA).
template <typename AT>
__global__ __launch_bounds__(256) void k_gemm(
    const AT* __restrict__ A, const u16* __restrict__ Bm,
    const float* __restrict__ bias, u16* __restrict__ C,
    int M, int N, int K)
{
    __shared__ u16 As[128 * 40];   // 32 k + 8 pad per row (80B stride, 16B aligned)
    __shared__ u16 Bs[128 * 40];
    const int m0 = blockIdx.y * 128, n0 = blockIdx.x * 128;
    const int t = threadIdx.x;
    const int wave = t >> 6, lane = t & 63;
    const int wm = wave & 1, wn = wave >> 1;
    const int lr = lane & 15, lq = lane >> 4;
    f32x4 acc[4][4] = {};
    const int sr = t >> 1, sp = t & 1;  // staging: 2 threads per row, 16 elems each
    const AT*  gA = A  + (size_t)(m0 + sr) * K + sp * 16;
    const u16* gB = Bm + (size_t)(n0 + sr) * K + sp * 16;
    u16* sA = As + sr * 40 + sp * 16;
    u16* sB = Bs + sr * 40 + sp * 16;
    for (int kt = 0; kt < K; kt += 32) {
        uint4 av0, av1;
        if constexpr (sizeof(AT) == 4) {       // f32 A: load 16 floats, cvt to f16
            float4 a0 = ((const float4*)gA)[0], a1 = ((const float4*)gA)[1];
            float4 a2 = ((const float4*)gA)[2], a3 = ((const float4*)gA)[3];
            f16x8 lo, hi;
            lo[0]=(_Float16)a0.x; lo[1]=(_Float16)a0.y; lo[2]=(_Float16)a0.z; lo[3]=(_Float16)a0.w;
            lo[4]=(_Float16)a1.x; lo[5]=(_Float16)a1.y; lo[6]=(_Float16)a1.z; lo[7]=(_Float16)a1.w;
            hi[0]=(_Float16)a2.x; hi[1]=(_Float16)a2.y; hi[2]=(_Float16)a2.z; hi[3]=(_Float16)a2.w;
            hi[4]=(_Float16)a3.x; hi[5]=(_Float16)a3.y; hi[6]=(_Float16)a3.z; hi[7]=(_Float16)a3.w;
            av0 = __builtin_bit_cast(uint4, lo);
            av1 = __builtin_bit_cast(uint4, hi);
        } else {                               // f16 A: straight 32B
            av0 = ((const uint4*)gA)[0];
            av1 = ((const uint4*)gA)[1];
        }
        uint4 b0 = ((const uint4*)gB)[0], b1 = ((const uint4*)gB)[1];
        gA += 32; gB += 32;
        __syncthreads();
        ((uint4*)sA)[0] = av0; ((uint4*)sA)[1] = av1;
        ((uint4*)sB)[0] = b0;  ((uint4*)sB)[1] = b1;
        __syncthreads();
        f16x8 af[4], bf[4];
#pragma unroll
        for (int i = 0; i < 4; i++)
            af[i] = *(const f16x8*)(As + (wm * 64 + i * 16 + lr) * 40 + lq * 8);
#pragma unroll
        for (int j = 0; j < 4; j++)
            bf[j] = *(const f16x8*)(Bs + (wn * 64 + j * 16 + lr) * 40 + lq * 8);
#pragma unroll
        for (int i = 0; i < 4; i++)
#pragma unroll
            for (int j = 0; j < 4; j++)
                acc[i][j] = __builtin_amdgcn_mfma_f32_16x16x32_f16(af[i], bf[j], acc[i][j], 0, 0, 0);
    }
#pragma unroll
    for (int i = 0; i < 4; i++) {
        int row = m0 + wm * 64 + i * 16 + lq * 4;
#pragma unroll
        for (int j = 0; j < 4; j++) {
            int col = n0 + wn * 64 + j * 16 + lr;
            float bv = bias[col];
#pragma unroll
            for (int rr = 0; rr < 4; rr++) {
                _Float16 v = (_Float16)(acc[i][j][rr] + bv);
                C[(size_t)(row + rr) * N + col] = __builtin_bit_cast(u16, v);
            }
        }
    }
}

// ---- GRU recurrence: one 256-thread WG per graph. Thread tid owns W_hh rows
// {tid, tid+256, tid+512} (r/z/n rows of h-index tid) = 96 uint4 = 384 regs,
// within the 512-reg/thread budget of a 4-wave WG (1 wave/SIMD) — unlike the
// 768-thread version whose 170-reg cap forced W back to L2 (R4/R5: 1.33us/step
// L2-bound). All three gates for h-index tid are local -> no gh LDS staging.
__global__ __launch_bounds__(256, 1) void k_rec(
    const u16* __restrict__ gx,          // [N_NODES][768] f16 input gates (incl. b_ih)
    const uint4* __restrict__ wsw,       // swizzled f16 W_hh (k_swz layout)
    const float* __restrict__ bhh,       // [768] f32
    const int*   __restrict__ starts,    // [129]
    u16* __restrict__ hout,              // f16 h [N_NODES][256] (layer 0) or null
    float* __restrict__ out)             // [128][256] f32 mean (layer 1) or null
{
    __shared__ uint4 hpk4[HIDDEN / 8];   // h packed as 256 f16 (32 uint4)
    const int g = blockIdx.x;
    const int tid = threadIdx.x;         // = h index
    const int wv = tid >> 6, l = tid & 63;
    const int start = starts[g];
    const int len = starts[g + 1] - start;
    // register-resident weight rows (coalesced fill thanks to swizzle)
    uint4 w[3][32];
#pragma unroll
    for (int rg = 0; rg < 3; rg++)
#pragma unroll
        for (int i = 0; i < 32; i++)
            w[rg][i] = wsw[(size_t)((wv * 3 + rg) * 32 + i) * 64 + l];
    const float bhr = bhh[tid], bhz = bhh[tid + 256], bhn = bhh[tid + 512];
    if (tid < 32) hpk4[tid] = make_uint4(0, 0, 0, 0);
    float hp = 0.f, hs = 0.f;
    const _Float16* gxr = (const _Float16*)gx + (size_t)start * G3 + tid;
    u16* hrow = hout ? (hout + (size_t)start * HIDDEN + tid) : (u16*)nullptr;
    __syncthreads();
    // depth-2 gx prefetch (covers HBM latency at 1 wave/SIMD)
    float g0r = 0, g0z = 0, g0n = 0, g1r = 0, g1z = 0, g1n = 0;
    if (len > 0) {
        g0r = (float)gxr[0]; g0z = (float)gxr[256]; g0n = (float)gxr[512];
        size_t o1 = (size_t)(len > 1 ? 1 : 0) * G3;
        g1r = (float)gxr[o1]; g1z = (float)gxr[o1 + 256]; g1n = (float)gxr[o1 + 512];
    }
    for (int t = 0; t < len; ++t) {
        int tp = t + 2 < len ? t + 2 : len - 1;
        size_t op = (size_t)tp * G3;
        float g2r = (float)gxr[op], g2z = (float)gxr[op + 256], g2n = (float)gxr[op + 512];
        float ar0 = bhr, ar1 = 0.f, ar2 = 0.f, ar3 = 0.f;
        float az0 = bhz, az1 = 0.f, az2 = 0.f, az3 = 0.f;
        float an0 = bhn, an1 = 0.f, an2 = 0.f, an3 = 0.f;
#pragma unroll
        for (int i = 0; i < 32; i++) {
            uint4 hv = hpk4[i];                        // uniform-address broadcast b128
            half2_t hx = __builtin_bit_cast(half2_t, hv.x), hy = __builtin_bit_cast(half2_t, hv.y);
            half2_t hz = __builtin_bit_cast(half2_t, hv.z), hw = __builtin_bit_cast(half2_t, hv.w);
            ar0 = __builtin_amdgcn_fdot2(__builtin_bit_cast(half2_t, w[0][i].x), hx, ar0, false);
            ar1 = __builtin_amdgcn_fdot2(__builtin_bit_cast(half2_t, w[0][i].y), hy, ar1, false);
            ar2 = __builtin_amdgcn_fdot2(__builtin_bit_cast(half2_t, w[0][i].z), hz, ar2, false);
            ar3 = __builtin_amdgcn_fdot2(__builtin_bit_cast(half2_t, w[0][i].w), hw, ar3, false);
            az0 = __builtin_amdgcn_fdot2(__builtin_bit_cast(half2_t, w[1][i].x), hx, az0, false);
            az1 = __builtin_amdgcn_fdot2(__builtin_bit_cast(half2_t, w[1][i].y), hy, az1, false);
            az2 = __builtin_amdgcn_fdot2(__builtin_bit_cast(half2_t, w[1][i].z), hz, az2, false);
            az3 = __builtin_amdgcn_fdot2(__builtin_bit_cast(half2_t, w[1][i].w), hw, az3, false);
            an0 = __builtin_amdgcn_fdot2(__builtin_bit_cast(half2_t, w[2][i].x), hx, an0, false);
            an1 = __builtin_amdgcn_fdot2(__builtin_bit_cast(half2_t, w[2][i].y), hy, an1, false);
            an2 = __builtin_amdgcn_fdot2(__builtin_bit_cast(half2_t, w[2][i].z), hz, an2, false);
            an3 = __builtin_amdgcn_fdot2(__builtin_bit_cast(half2_t, w[2][i].w), hw, an3, false);
        }
        float ghr = (ar0 + ar1) + (ar2 + ar3);
        float ghz = (az0 + az1) + (az2 + az3);
        float ghn = (an0 + an1) + (an2 + an3);
        float r = sigf(g0r + ghr);
        float z = sigf(g0z + ghz);
        float n = tanhfast(g0n + r * ghn);
        float h = (1.f - z) * n + z * hp;
        hp = h; hs += h;
        _Float16 ph = (_Float16)h;
        u16 pk = __builtin_bit_cast(u16, ph);
        __syncthreads();                               // all reads of hpk4 done
        ((u16*)hpk4)[tid] = pk;
        if (hrow) hrow[(size_t)t * HIDDEN] = pk;
        g0r = g1r; g0z = g1z; g0n = g1n;
        g1r = g2r; g1z = g2z; g1n = g2n;
        __syncthreads();                               // new h visible
    }
    if (out) {
        float inv = 1.f / (float)(len > 0 ? len : 1);
        out[g * HIDDEN + tid] = hs * inv;              // f32 output
    }
}

extern "C" void kernel_launch(void* const* d_in, const int* in_sizes, int n_in,
                              void* d_out, int out_size, void* d_ws, size_t ws_size,
                              hipStream_t stream)
{
    const float* x     = (const float*)d_in[0];
    const int*   batch = (const int*)d_in[1];
    const float* Wih0  = (const float*)d_in[2];
    const float* Whh0  = (const float*)d_in[3];
    const float* bih0  = (const float*)d_in[4];
    const float* bhh0  = (const float*)d_in[5];
    const float* Wih1  = (const float*)d_in[6];
    const float* Whh1  = (const float*)d_in[7];
    const float* bih1  = (const float*)d_in[8];
    const float* bhh1  = (const float*)d_in[9];
    float* out = (float*)d_out;

    // Workspace ~135.5 MB
    char* ws = (char*)d_ws;
    size_t o = 0;
    int*   starts = (int*)  (ws + o); o += 4096;
    u16*   wi0    = (u16*)  (ws + o); o += (size_t)G3 * IN_DIM * 2;      // 384 KB (f16 W_ih0)
    u16*   wi1    = (u16*)  (ws + o); o += (size_t)G3 * HIDDEN * 2;     // 384 KB (f16 W_ih1)
    uint4* wsw0   = (uint4*)(ws + o); o += (size_t)G3 * HIDDEN * 2;     // 384 KB
    uint4* wsw1   = (uint4*)(ws + o); o += (size_t)G3 * HIDDEN * 2;     // 384 KB
    u16*   h0     = (u16*)  (ws + o); o += (size_t)N_NODES * HIDDEN * 2; // 33.5 MB (f16)
    u16*   gxbuf  = (u16*)  (ws + o); o += (size_t)N_NODES * G3 * 2;     // 100.7 MB (f16, reused)

    k_starts<<<1, 256, 0, stream>>>(batch, starts, N_NODES, NGRAPH);
    k_cvt8<<<96, 256, 0, stream>>>(Wih0, wi0, G3 * IN_DIM);
    k_cvt8<<<96, 256, 0, stream>>>(Wih1, wi1, G3 * HIDDEN);
    k_swz<<<96, 256, 0, stream>>>(Whh0, wsw0);
    k_swz<<<96, 256, 0, stream>>>(Whh1, wsw1);

    // layer 0: gx0 = x*Wih0^T + bih0 (A staged f32->f16); rec -> h0 (f16)
    k_gemm<float><<<dim3(G3 / 128, N_NODES / 128), 256, 0, stream>>>(x, wi0, bih0, gxbuf, N_NODES, G3, IN_DIM);
    k_rec<<<NGRAPH, 256, 0, stream>>>(gxbuf, wsw0, bhh0, starts, h0, (float*)nullptr);
    // layer 1: gx1 = h0*Wih1^T + bih1 (f16 MFMA); rec + masked mean -> out (f32)
    k_gemm<_Float16><<<dim3(G3 / 128, N_NODES / 128), 256, 0, stream>>>((const _Float16*)h0, wi1, bih1, gxbuf, N_NODES, G3, HIDDEN);
    k_rec<<<NGRAPH, 256, 0, stream>>>(gxbuf, wsw1, bhh1, starts, (u16*)nullptr, out);
}

// Round 7
// 1794.635 us; speedup vs baseline: 1.4343x; 1.4343x over previous
//
#include <hip/hip_runtime.h>
#include <hip/hip_bf16.h>

typedef _Float16 half2_t __attribute__((ext_vector_type(2)));
typedef _Float16 f16x8   __attribute__((ext_vector_type(8)));
typedef float    f32x4   __attribute__((ext_vector_type(4)));
typedef unsigned short u16;
typedef unsigned int   u32;

#define N_NODES 65536
#define IN_DIM  256
#define HIDDEN  256
#define G3      768     // 3*HIDDEN gate rows
#define NGRAPH  128

__device__ __forceinline__ float sigf(float x)    { return 1.f / (1.f + __expf(-x)); }
__device__ __forceinline__ float tanhfast(float x){ return 2.f / (1.f + __expf(-2.f * x)) - 1.f; }

// ---- per-graph starts via binary search on sorted batch (int32/int64 autodetect) ----
__global__ void k_starts(const int* __restrict__ batch, int* __restrict__ starts, int n, int ngraph) {
    int g = blockIdx.x * blockDim.x + threadIdx.x;
    if (g > ngraph) return;
    int stride = (batch[n - 1] == 0) ? 2 : 1;
    if (g == ngraph) { starts[g] = n; return; }
    int lo = 0, hi = n;
    while (lo < hi) { int mid = (lo + hi) >> 1; if (batch[(size_t)mid * stride] < g) lo = mid + 1; else hi = mid; }
    starts[g] = lo;
}

// ---- f32 -> f16 elementwise (n multiple of 8) ----
__global__ void k_cvt8(const float* __restrict__ s, u16* __restrict__ d, int n) {
    int t = blockIdx.x * 256 + threadIdx.x;
    int i = t * 8;
    if (i >= n) return;
    float4 a = ((const float4*)(s + i))[0];
    float4 b = ((const float4*)(s + i))[1];
    f16x8 o;
    o[0] = (_Float16)a.x; o[1] = (_Float16)a.y; o[2] = (_Float16)a.z; o[3] = (_Float16)a.w;
    o[4] = (_Float16)b.x; o[5] = (_Float16)b.y; o[6] = (_Float16)b.z; o[7] = (_Float16)b.w;
    *(f16x8*)(d + i) = o;
}

// ---- W_hh f32 [768][256] -> swizzled f16 chunks for k_rec's 512-thread layout.
// t = (((w*3 + rg)*16 + i)*64 + l): wave w=0..7 (w&3 = h-group, w>>2 = k-half),
// rg = gate 0..2, i = k-chunk 0..15, lane l. Holds
// W_hh[rg*256 + (w&3)*64 + l][(w>>2)*128 + 8i .. +7] as 8 f16.
__global__ void k_swz(const float* __restrict__ W, uint4* __restrict__ out) {
    int t = blockIdx.x * 256 + threadIdx.x;
    if (t >= 24576) return;
    int l = t & 63, i = (t >> 6) & 15, rest = t >> 10;  // rest = w*3+rg, 0..23
    int w = rest / 3, rg = rest % 3;
    int row = rg * 256 + (w & 3) * 64 + l;
    int col = (w >> 2) * 128 + i * 8;
    const float* s = W + row * 256 + col;
    f16x8 o;
#pragma unroll
    for (int q = 0; q < 8; q++) o[q] = (_Float16)s[q];
    out[t] = __builtin_bit_cast(uint4, o);
}

// ---- GEMM: C[M][N] f16 = A[M][K] * B[N][K]^T + bias[N]
// A is f32 (converted during LDS staging) or f16. 128x128 tile per 256-thread
// WG, 4 waves each 64x64 (4x4 of 16x16x32 f16 MFMA).
template <typename AT>
__global__ __launch_bounds__(256) void k_gemm(
    const AT* __restrict__ A, const u16* __restrict__ Bm,
    const float* __restrict__ bias, u16* __restrict__ C,
    int M, int N, int K)
{
    __shared__ u16 As[128 * 40];   // 32 k + 8 pad per row (80B stride, 16B aligned)
    __shared__ u16 Bs[128 * 40];
    const int m0 = blockIdx.y * 128, n0 = blockIdx.x * 128;
    const int t = threadIdx.x;
    const int wave = t >> 6, lane = t & 63;
    const int wm = wave & 1, wn = wave >> 1;
    const int lr = lane & 15, lq = lane >> 4;
    f32x4 acc[4][4] = {};
    const int sr = t >> 1, sp = t & 1;  // staging: 2 threads per row, 16 elems each
    const AT*  gA = A  + (size_t)(m0 + sr) * K + sp * 16;
    const u16* gB = Bm + (size_t)(n0 + sr) * K + sp * 16;
    u16* sA = As + sr * 40 + sp * 16;
    u16* sB = Bs + sr * 40 + sp * 16;
    for (int kt = 0; kt < K; kt += 32) {
        uint4 av0, av1;
        if constexpr (sizeof(AT) == 4) {       // f32 A: load 16 floats, cvt to f16
            float4 a0 = ((const float4*)gA)[0], a1 = ((const float4*)gA)[1];
            float4 a2 = ((const float4*)gA)[2], a3 = ((const float4*)gA)[3];
            f16x8 lo, hi;
            lo[0]=(_Float16)a0.x; lo[1]=(_Float16)a0.y; lo[2]=(_Float16)a0.z; lo[3]=(_Float16)a0.w;
            lo[4]=(_Float16)a1.x; lo[5]=(_Float16)a1.y; lo[6]=(_Float16)a1.z; lo[7]=(_Float16)a1.w;
            hi[0]=(_Float16)a2.x; hi[1]=(_Float16)a2.y; hi[2]=(_Float16)a2.z; hi[3]=(_Float16)a2.w;
            hi[4]=(_Float16)a3.x; hi[5]=(_Float16)a3.y; hi[6]=(_Float16)a3.z; hi[7]=(_Float16)a3.w;
            av0 = __builtin_bit_cast(uint4, lo);
            av1 = __builtin_bit_cast(uint4, hi);
        } else {                               // f16 A: straight 32B
            av0 = ((const uint4*)gA)[0];
            av1 = ((const uint4*)gA)[1];
        }
        uint4 b0 = ((const uint4*)gB)[0], b1 = ((const uint4*)gB)[1];
        gA += 32; gB += 32;
        __syncthreads();
        ((uint4*)sA)[0] = av0; ((uint4*)sA)[1] = av1;
        ((uint4*)sB)[0] = b0;  ((uint4*)sB)[1] = b1;
        __syncthreads();
        f16x8 af[4], bf[4];
#pragma unroll
        for (int i = 0; i < 4; i++)
            af[i] = *(const f16x8*)(As + (wm * 64 + i * 16 + lr) * 40 + lq * 8);
#pragma unroll
        for (int j = 0; j < 4; j++)
            bf[j] = *(const f16x8*)(Bs + (wn * 64 + j * 16 + lr) * 40 + lq * 8);
#pragma unroll
        for (int i = 0; i < 4; i++)
#pragma unroll
            for (int j = 0; j < 4; j++)
                acc[i][j] = __builtin_amdgcn_mfma_f32_16x16x32_f16(af[i], bf[j], acc[i][j], 0, 0, 0);
    }
#pragma unroll
    for (int i = 0; i < 4; i++) {
        int row = m0 + wm * 64 + i * 16 + lq * 4;
#pragma unroll
        for (int j = 0; j < 4; j++) {
            int col = n0 + wn * 64 + j * 16 + lr;
            float bv = bias[col];
#pragma unroll
            for (int rr = 0; rr < 4; rr++) {
                _Float16 v = (_Float16)(acc[i][j][rr] + bv);
                C[(size_t)(row + rr) * N + col] = __builtin_bit_cast(u16, v);
            }
        }
    }
}

// ---- GRU recurrence: one 512-thread WG per graph (8 waves = 2/SIMD -> 256-reg
// budget). Thread (kh=tid>>8, h=tid&255) owns k-half kh of W_hh rows
// {h, h+256, h+512} = 48 uint4 = 192 VGPRs (R6 proved the allocator keeps up
// to ~212 live; 384 was over the 256 ArchVGPR cap and got sunk to L2).
// kh=1 folds xr/xz into its partials (xn separate: n = tanh(xn + r*gh_n)) and
// owns the gx prefetch; kh=0 combines partials + gate math + h update.
__global__ __launch_bounds__(512, 2) void k_rec(
    const u16* __restrict__ gx,          // [N_NODES][768] f16 input gates (incl. b_ih)
    const uint4* __restrict__ wsw,       // swizzled f16 W_hh (k_swz layout)
    const float* __restrict__ bhh,       // [768] f32
    const int*   __restrict__ starts,    // [129]
    u16* __restrict__ hout,              // f16 h [N_NODES][256] (layer 0) or null
    float* __restrict__ out)             // [128][256] f32 mean (layer 1) or null
{
    __shared__ float part[4][HIDDEN];    // r,z,n dot-partials + xn from kh=1
    __shared__ uint4 hpk4[HIDDEN / 8];   // h packed as 256 f16 (32 uint4)
    const int g = blockIdx.x;
    const int tid = threadIdx.x;
    const int h = tid & 255;
    const int kh = tid >> 8;
    const int wv = tid >> 6, l = tid & 63;
    const int start = starts[g];
    const int len = starts[g + 1] - start;
    // register-resident weight half-rows (coalesced fill thanks to swizzle)
    uint4 w[3][16];
#pragma unroll
    for (int rg = 0; rg < 3; rg++)
#pragma unroll
        for (int i = 0; i < 16; i++)
            w[rg][i] = wsw[(size_t)(((wv * 3 + rg) * 16 + i) * 64 + l)];
#pragma unroll
    for (int rg = 0; rg < 3; rg++)
#pragma unroll
        for (int i = 0; i < 16; i++)
            asm volatile("" : "+v"(w[rg][i].x), "+v"(w[rg][i].y), "+v"(w[rg][i].z), "+v"(w[rg][i].w));
    const float bhr = bhh[h], bhz = bhh[h + 256], bhn = bhh[h + 512];
    if (tid < HIDDEN / 8) hpk4[tid] = make_uint4(0, 0, 0, 0);
    float hp = 0.f, hs = 0.f;
    const _Float16* gxr = (const _Float16*)gx + (size_t)start * G3 + h;
    u16* hrow = hout ? (hout + (size_t)start * HIDDEN + h) : (u16*)nullptr;
    float gr = 0.f, gz = 0.f, gn = 0.f;
    if (kh && len > 0) { gr = (float)gxr[0]; gz = (float)gxr[256]; gn = (float)gxr[512]; }
    __syncthreads();
    for (int t = 0; t < len; ++t) {
        float pr = 0.f, pz = 0.f, pn = 0.f;
        if (kh) {                                  // prefetch next step's gx
            int tn = t + 1 < len ? t + 1 : len - 1;
            size_t o1 = (size_t)tn * G3;
            pr = (float)gxr[o1]; pz = (float)gxr[o1 + 256]; pn = (float)gxr[o1 + 512];
        }
        // init: kh=0 carries biases; kh=1 carries xr/xz (xn kept separate)
        float ar0 = kh ? gr : bhr, ar1 = 0.f;
        float az0 = kh ? gz : bhz, az1 = 0.f;
        float an0 = kh ? 0.f : bhn, an1 = 0.f;
#pragma unroll
        for (int i = 0; i < 16; i++) {
            uint4 hv = hpk4[kh * 16 + i];          // wave-uniform broadcast b128
            half2_t hx = __builtin_bit_cast(half2_t, hv.x), hy = __builtin_bit_cast(half2_t, hv.y);
            half2_t hz2 = __builtin_bit_cast(half2_t, hv.z), hw = __builtin_bit_cast(half2_t, hv.w);
            ar0 = __builtin_amdgcn_fdot2(__builtin_bit_cast(half2_t, w[0][i].x), hx, ar0, false);
            ar1 = __builtin_amdgcn_fdot2(__builtin_bit_cast(half2_t, w[0][i].y), hy, ar1, false);
            ar0 = __builtin_amdgcn_fdot2(__builtin_bit_cast(half2_t, w[0][i].z), hz2, ar0, false);
            ar1 = __builtin_amdgcn_fdot2(__builtin_bit_cast(half2_t, w[0][i].w), hw, ar1, false);
            az0 = __builtin_amdgcn_fdot2(__builtin_bit_cast(half2_t, w[1][i].x), hx, az0, false);
            az1 = __builtin_amdgcn_fdot2(__builtin_bit_cast(half2_t, w[1][i].y), hy, az1, false);
            az0 = __builtin_amdgcn_fdot2(__builtin_bit_cast(half2_t, w[1][i].z), hz2, az0, false);
            az1 = __builtin_amdgcn_fdot2(__builtin_bit_cast(half2_t, w[1][i].w), hw, az1, false);
            an0 = __builtin_amdgcn_fdot2(__builtin_bit_cast(half2_t, w[2][i].x), hx, an0, false);
            an1 = __builtin_amdgcn_fdot2(__builtin_bit_cast(half2_t, w[2][i].y), hy, an1, false);
            an0 = __builtin_amdgcn_fdot2(__builtin_bit_cast(half2_t, w[2][i].z), hz2, an0, false);
            an1 = __builtin_amdgcn_fdot2(__builtin_bit_cast(half2_t, w[2][i].w), hw, an1, false);
        }
        float sr = ar0 + ar1, sz = az0 + az1, sn = an0 + an1;
        if (kh) { part[0][h] = sr; part[1][h] = sz; part[2][h] = sn; part[3][h] = gn; }
        __syncthreads();
        if (!kh) {
            float r = sigf(sr + part[0][h]);
            float z = sigf(sz + part[1][h]);
            float n = tanhfast(part[3][h] + r * (sn + part[2][h]));
            float hnew = (1.f - z) * n + z * hp;
            hp = hnew; hs += hnew;
            _Float16 ph = (_Float16)hnew;
            u16 pk = __builtin_bit_cast(u16, ph);
            ((u16*)hpk4)[h] = pk;
            if (hrow) hrow[(size_t)t * HIDDEN] = pk;
        }
        gr = pr; gz = pz; gn = pn;
        __syncthreads();
    }
    if (out && !kh) {
        float inv = 1.f / (float)(len > 0 ? len : 1);
        out[g * HIDDEN + h] = hs * inv;            // f32 output
    }
}

extern "C" void kernel_launch(void* const* d_in, const int* in_sizes, int n_in,
                              void* d_out, int out_size, void* d_ws, size_t ws_size,
                              hipStream_t stream)
{
    const float* x     = (const float*)d_in[0];
    const int*   batch = (const int*)d_in[1];
    const float* Wih0  = (const float*)d_in[2];
    const float* Whh0  = (const float*)d_in[3];
    const float* bih0  = (const float*)d_in[4];
    const float* bhh0  = (const float*)d_in[5];
    const float* Wih1  = (const float*)d_in[6];
    const float* Whh1  = (const float*)d_in[7];
    const float* bih1  = (const float*)d_in[8];
    const float* bhh1  = (const float*)d_in[9];
    float* out = (float*)d_out;

    // Workspace ~135.5 MB
    char* ws = (char*)d_ws;
    size_t o = 0;
    int*   starts = (int*)  (ws + o); o += 4096;
    u16*   wi0    = (u16*)  (ws + o); o += (size_t)G3 * IN_DIM * 2;      // 384 KB (f16 W_ih0)
    u16*   wi1    = (u16*)  (ws + o); o += (size_t)G3 * HIDDEN * 2;     // 384 KB (f16 W_ih1)
    uint4* wsw0   = (uint4*)(ws + o); o += (size_t)G3 * HIDDEN * 2;     // 384 KB
    uint4* wsw1   = (uint4*)(ws + o); o += (size_t)G3 * HIDDEN * 2;     // 384 KB
    u16*   h0     = (u16*)  (ws + o); o += (size_t)N_NODES * HIDDEN * 2; // 33.5 MB (f16)
    u16*   gxbuf  = (u16*)  (ws + o); o += (size_t)N_NODES * G3 * 2;     // 100.7 MB (f16, reused)

    k_starts<<<1, 256, 0, stream>>>(batch, starts, N_NODES, NGRAPH);
    k_cvt8<<<96, 256, 0, stream>>>(Wih0, wi0, G3 * IN_DIM);
    k_cvt8<<<96, 256, 0, stream>>>(Wih1, wi1, G3 * HIDDEN);
    k_swz<<<96, 256, 0, stream>>>(Whh0, wsw0);
    k_swz<<<96, 256, 0, stream>>>(Whh1, wsw1);

    // layer 0: gx0 = x*Wih0^T + bih0 (A staged f32->f16); rec -> h0 (f16)
    k_gemm<float><<<dim3(G3 / 128, N_NODES / 128), 256, 0, stream>>>(x, wi0, bih0, gxbuf, N_NODES, G3, IN_DIM);
    k_rec<<<NGRAPH, 512, 0, stream>>>(gxbuf, wsw0, bhh0, starts, h0, (float*)nullptr);
    // layer 1: gx1 = h0*Wih1^T + bih1 (f16 MFMA); rec + masked mean -> out (f32)
    k_gemm<_Float16><<<dim3(G3 / 128, N_NODES / 128), 256, 0, stream>>>((const _Float16*)h0, wi1, bih1, gxbuf, N_NODES, G3, HIDDEN);
    k_rec<<<NGRAPH, 512, 0, stream>>>(gxbuf, wsw1, bhh1, starts, (u16*)nullptr, out);
}

// Round 8
// 1548.610 us; speedup vs baseline: 1.6621x; 1.1589x over previous
//
#include <hip/hip_runtime.h>
#include <hip/hip_bf16.h>

typedef _Float16 half2_t __attribute__((ext_vector_type(2)));
typedef _Float16 f16x8   __attribute__((ext_vector_type(8)));
typedef float    f32x4   __attribute__((ext_vector_type(4)));
typedef unsigned short u16;
typedef unsigned int   u32;

#define N_NODES 65536
#define IN_DIM  256
#define HIDDEN  256
#define G3      768     // 3*HIDDEN gate rows
#define NGRAPH  128

__device__ __forceinline__ float sigf(float x)    { return 1.f / (1.f + __expf(-x)); }
__device__ __forceinline__ float tanhfast(float x){ return 2.f / (1.f + __expf(-2.f * x)) - 1.f; }

// ---- per-graph starts via binary search on sorted batch (int32/int64 autodetect) ----
__global__ void k_starts(const int* __restrict__ batch, int* __restrict__ starts, int n, int ngraph) {
    int g = blockIdx.x * blockDim.x + threadIdx.x;
    if (g > ngraph) return;
    int stride = (batch[n - 1] == 0) ? 2 : 1;
    if (g == ngraph) { starts[g] = n; return; }
    int lo = 0, hi = n;
    while (lo < hi) { int mid = (lo + hi) >> 1; if (batch[(size_t)mid * stride] < g) lo = mid + 1; else hi = mid; }
    starts[g] = lo;
}

// ---- f32 -> f16 elementwise (n multiple of 8) ----
__global__ void k_cvt8(const float* __restrict__ s, u16* __restrict__ d, int n) {
    int t = blockIdx.x * 256 + threadIdx.x;
    int i = t * 8;
    if (i >= n) return;
    float4 a = ((const float4*)(s + i))[0];
    float4 b = ((const float4*)(s + i))[1];
    f16x8 o;
    o[0] = (_Float16)a.x; o[1] = (_Float16)a.y; o[2] = (_Float16)a.z; o[3] = (_Float16)a.w;
    o[4] = (_Float16)b.x; o[5] = (_Float16)b.y; o[6] = (_Float16)b.z; o[7] = (_Float16)b.w;
    *(f16x8*)(d + i) = o;
}

// ---- W_hh f32 [768][256] -> swizzled f16 chunks for k_rec's 1024-thread layout.
// chunk c = ((wv*3 + rg)*8 + i)*64 + l  (wv = wave 0..15, rg = gate 0..2,
// i = k-chunk 0..7, l = lane). Holds
// W_hh[rg*256 + (wv&3)*64 + l][(wv>>2)*64 + 8i .. +7] as 8 f16 (one uint4).
__global__ void k_swz(const float* __restrict__ W, uint4* __restrict__ out) {
    int t = blockIdx.x * 256 + threadIdx.x;
    if (t >= 24576) return;
    int l = t & 63, i = (t >> 6) & 7, rest = t >> 9;  // rest = wv*3+rg, 0..47
    int wv = rest / 3, rg = rest % 3;
    int row = rg * 256 + (wv & 3) * 64 + l;
    int col = (wv >> 2) * 64 + i * 8;
    const float* s = W + row * 256 + col;
    f16x8 o;
#pragma unroll
    for (int q = 0; q < 8; q++) o[q] = (_Float16)s[q];
    out[t] = __builtin_bit_cast(uint4, o);
}

// ---- GEMM: C[M][N] f16 = A[M][K] * B[N][K]^T + bias[N]
// A is f32 (converted during LDS staging) or f16. 128x128 tile per 256-thread
// WG, 4 waves each 64x64 (4x4 of 16x16x32 f16 MFMA).
template <typename AT>
__global__ __launch_bounds__(256) void k_gemm(
    const AT* __restrict__ A, const u16* __restrict__ Bm,
    const float* __restrict__ bias, u16* __restrict__ C,
    int M, int N, int K)
{
    __shared__ u16 As[128 * 40];   // 32 k + 8 pad per row (80B stride, 16B aligned)
    __shared__ u16 Bs[128 * 40];
    const int m0 = blockIdx.y * 128, n0 = blockIdx.x * 128;
    const int t = threadIdx.x;
    const int wave = t >> 6, lane = t & 63;
    const int wm = wave & 1, wn = wave >> 1;
    const int lr = lane & 15, lq = lane >> 4;
    f32x4 acc[4][4] = {};
    const int sr = t >> 1, sp = t & 1;  // staging: 2 threads per row, 16 elems each
    const AT*  gA = A  + (size_t)(m0 + sr) * K + sp * 16;
    const u16* gB = Bm + (size_t)(n0 + sr) * K + sp * 16;
    u16* sA = As + sr * 40 + sp * 16;
    u16* sB = Bs + sr * 40 + sp * 16;
    for (int kt = 0; kt < K; kt += 32) {
        uint4 av0, av1;
        if constexpr (sizeof(AT) == 4) {       // f32 A: load 16 floats, cvt to f16
            float4 a0 = ((const float4*)gA)[0], a1 = ((const float4*)gA)[1];
            float4 a2 = ((const float4*)gA)[2], a3 = ((const float4*)gA)[3];
            f16x8 lo, hi;
            lo[0]=(_Float16)a0.x; lo[1]=(_Float16)a0.y; lo[2]=(_Float16)a0.z; lo[3]=(_Float16)a0.w;
            lo[4]=(_Float16)a1.x; lo[5]=(_Float16)a1.y; lo[6]=(_Float16)a1.z; lo[7]=(_Float16)a1.w;
            hi[0]=(_Float16)a2.x; hi[1]=(_Float16)a2.y; hi[2]=(_Float16)a2.z; hi[3]=(_Float16)a2.w;
            hi[4]=(_Float16)a3.x; hi[5]=(_Float16)a3.y; hi[6]=(_Float16)a3.z; hi[7]=(_Float16)a3.w;
            av0 = __builtin_bit_cast(uint4, lo);
            av1 = __builtin_bit_cast(uint4, hi);
        } else {                               // f16 A: straight 32B
            av0 = ((const uint4*)gA)[0];
            av1 = ((const uint4*)gA)[1];
        }
        uint4 b0 = ((const uint4*)gB)[0], b1 = ((const uint4*)gB)[1];
        gA += 32; gB += 32;
        __syncthreads();
        ((uint4*)sA)[0] = av0; ((uint4*)sA)[1] = av1;
        ((uint4*)sB)[0] = b0;  ((uint4*)sB)[1] = b1;
        __syncthreads();
        f16x8 af[4], bf[4];
#pragma unroll
        for (int i = 0; i < 4; i++)
            af[i] = *(const f16x8*)(As + (wm * 64 + i * 16 + lr) * 40 + lq * 8);
#pragma unroll
        for (int j = 0; j < 4; j++)
            bf[j] = *(const f16x8*)(Bs + (wn * 64 + j * 16 + lr) * 40 + lq * 8);
#pragma unroll
        for (int i = 0; i < 4; i++)
#pragma unroll
            for (int j = 0; j < 4; j++)
                acc[i][j] = __builtin_amdgcn_mfma_f32_16x16x32_f16(af[i], bf[j], acc[i][j], 0, 0, 0);
    }
#pragma unroll
    for (int i = 0; i < 4; i++) {
        int row = m0 + wm * 64 + i * 16 + lq * 4;
#pragma unroll
        for (int j = 0; j < 4; j++) {
            int col = n0 + wn * 64 + j * 16 + lr;
            float bv = bias[col];
#pragma unroll
            for (int rr = 0; rr < 4; rr++) {
                _Float16 v = (_Float16)(acc[i][j][rr] + bv);
                C[(size_t)(row + rr) * N + col] = __builtin_bit_cast(u16, v);
            }
        }
    }
}

// ---- GRU recurrence: one 1024-thread WG per graph (16 waves = 4/SIMD, 128-reg
// cap). Thread (q=tid>>8, h=tid&255) owns k-quarter q of W_hh rows
// {h, h+256, h+512} = 24 uint4 = 96 VGPRs — below the ~116-dword threshold the
// allocator demonstrably keeps resident (R7). No asm pins (they force scratch
// spills, R5/R7). q>0 write 3 dot-partials to LDS; q=0 combines (+bhh from
// partial slot 0), gate math, h update. L2 W-traffic eliminated.
__global__ __launch_bounds__(1024, 4) void k_rec(
    const u16* __restrict__ gx,          // [N_NODES][768] f16 input gates (incl. b_ih)
    const uint4* __restrict__ wsw,       // swizzled f16 W_hh (k_swz layout)
    const float* __restrict__ bhh,       // [768] f32
    const int*   __restrict__ starts,    // [129]
    u16* __restrict__ hout,              // f16 h [N_NODES][256] (layer 0) or null
    float* __restrict__ out)             // [128][256] f32 mean (layer 1) or null
{
    __shared__ float part[3][4][HIDDEN]; // [gate][quarter][h]; slot q=0 holds bhh
    __shared__ uint4 hpk4[HIDDEN / 8];   // h packed as 256 f16 (32 uint4)
    const int g = blockIdx.x;
    const int tid = threadIdx.x;
    const int h = tid & 255;
    const int q = tid >> 8;
    const int wv = tid >> 6, l = tid & 63;
    const int start = starts[g];
    const int len = starts[g + 1] - start;
    // register-resident quarter-rows (coalesced fill thanks to swizzle)
    uint4 w[3][8];
#pragma unroll
    for (int rg = 0; rg < 3; rg++)
#pragma unroll
        for (int i = 0; i < 8; i++)
            w[rg][i] = wsw[(size_t)(((wv * 3 + rg) * 8 + i) * 64 + l)];
    if (tid < G3) part[tid >> 8][0][tid & 255] = bhh[tid];  // bias into slot 0
    if (tid < HIDDEN / 8) hpk4[tid] = make_uint4(0, 0, 0, 0);
    float hp = 0.f, hs = 0.f;
    const _Float16* gxr = (const _Float16*)gx + (size_t)start * G3 + h;
    u16* hrow = hout ? (hout + (size_t)start * HIDDEN + h) : (u16*)nullptr;
    float gr = 0.f, gz = 0.f, gn = 0.f;
    if (q == 0 && len > 0) { gr = (float)gxr[0]; gz = (float)gxr[256]; gn = (float)gxr[512]; }
    const int qb = q * 8;
    __syncthreads();
    for (int t = 0; t < len; ++t) {
        float pr = 0.f, pz = 0.f, pn = 0.f;
        if (q == 0) {                              // prefetch next step's gx
            int tn = t + 1 < len ? t + 1 : len - 1;
            size_t o1 = (size_t)tn * G3;
            pr = (float)gxr[o1]; pz = (float)gxr[o1 + 256]; pn = (float)gxr[o1 + 512];
        }
        float ar = 0.f, az = 0.f, an = 0.f;
#pragma unroll
        for (int i = 0; i < 8; i++) {
            uint4 hv = hpk4[qb + i];               // wave-uniform broadcast b128
            half2_t hx = __builtin_bit_cast(half2_t, hv.x), hy = __builtin_bit_cast(half2_t, hv.y);
            half2_t hz2 = __builtin_bit_cast(half2_t, hv.z), hw = __builtin_bit_cast(half2_t, hv.w);
            // gate-interleaved: dependent same-acc ops 3 insts apart (covers fdot2 latency)
            ar = __builtin_amdgcn_fdot2(__builtin_bit_cast(half2_t, w[0][i].x), hx, ar, false);
            az = __builtin_amdgcn_fdot2(__builtin_bit_cast(half2_t, w[1][i].x), hx, az, false);
            an = __builtin_amdgcn_fdot2(__builtin_bit_cast(half2_t, w[2][i].x), hx, an, false);
            ar = __builtin_amdgcn_fdot2(__builtin_bit_cast(half2_t, w[0][i].y), hy, ar, false);
            az = __builtin_amdgcn_fdot2(__builtin_bit_cast(half2_t, w[1][i].y), hy, az, false);
            an = __builtin_amdgcn_fdot2(__builtin_bit_cast(half2_t, w[2][i].y), hy, an, false);
            ar = __builtin_amdgcn_fdot2(__builtin_bit_cast(half2_t, w[0][i].z), hz2, ar, false);
            az = __builtin_amdgcn_fdot2(__builtin_bit_cast(half2_t, w[1][i].z), hz2, az, false);
            an = __builtin_amdgcn_fdot2(__builtin_bit_cast(half2_t, w[2][i].z), hz2, an, false);
            ar = __builtin_amdgcn_fdot2(__builtin_bit_cast(half2_t, w[0][i].w), hw, ar, false);
            az = __builtin_amdgcn_fdot2(__builtin_bit_cast(half2_t, w[1][i].w), hw, az, false);
            an = __builtin_amdgcn_fdot2(__builtin_bit_cast(half2_t, w[2][i].w), hw, an, false);
        }
        if (q) { part[0][q][h] = ar; part[1][q][h] = az; part[2][q][h] = an; }
        __syncthreads();
        if (!q) {
            float sr = ar + part[0][0][h] + part[0][1][h] + part[0][2][h] + part[0][3][h];
            float sz = az + part[1][0][h] + part[1][1][h] + part[1][2][h] + part[1][3][h];
            float sn = an + part[2][0][h] + part[2][1][h] + part[2][2][h] + part[2][3][h];
            float r = sigf(gr + sr);
            float z = sigf(gz + sz);
            float n = tanhfast(gn + r * sn);       // sn includes bhh_n (inside r*)
            float hnew = (1.f - z) * n + z * hp;
            hp = hnew; hs += hnew;
            _Float16 ph = (_Float16)hnew;
            u16 pk = __builtin_bit_cast(u16, ph);
            ((u16*)hpk4)[h] = pk;
            if (hrow) hrow[(size_t)t * HIDDEN] = pk;
            gr = pr; gz = pz; gn = pn;
        }
        __syncthreads();
    }
    if (out && !q) {
        float inv = 1.f / (float)(len > 0 ? len : 1);
        out[g * HIDDEN + h] = hs * inv;            // f32 output
    }
}

extern "C" void kernel_launch(void* const* d_in, const int* in_sizes, int n_in,
                              void* d_out, int out_size, void* d_ws, size_t ws_size,
                              hipStream_t stream)
{
    const float* x     = (const float*)d_in[0];
    const int*   batch = (const int*)d_in[1];
    const float* Wih0  = (const float*)d_in[2];
    const float* Whh0  = (const float*)d_in[3];
    const float* bih0  = (const float*)d_in[4];
    const float* bhh0  = (const float*)d_in[5];
    const float* Wih1  = (const float*)d_in[6];
    const float* Whh1  = (const float*)d_in[7];
    const float* bih1  = (const float*)d_in[8];
    const float* bhh1  = (const float*)d_in[9];
    float* out = (float*)d_out;

    // Workspace ~135.5 MB
    char* ws = (char*)d_ws;
    size_t o = 0;
    int*   starts = (int*)  (ws + o); o += 4096;
    u16*   wi0    = (u16*)  (ws + o); o += (size_t)G3 * IN_DIM * 2;      // 384 KB (f16 W_ih0)
    u16*   wi1    = (u16*)  (ws + o); o += (size_t)G3 * HIDDEN * 2;     // 384 KB (f16 W_ih1)
    uint4* wsw0   = (uint4*)(ws + o); o += (size_t)G3 * HIDDEN * 2;     // 384 KB
    uint4* wsw1   = (uint4*)(ws + o); o += (size_t)G3 * HIDDEN * 2;     // 384 KB
    u16*   h0     = (u16*)  (ws + o); o += (size_t)N_NODES * HIDDEN * 2; // 33.5 MB (f16)
    u16*   gxbuf  = (u16*)  (ws + o); o += (size_t)N_NODES * G3 * 2;     // 100.7 MB (f16, reused)

    k_starts<<<1, 256, 0, stream>>>(batch, starts, N_NODES, NGRAPH);
    k_cvt8<<<96, 256, 0, stream>>>(Wih0, wi0, G3 * IN_DIM);
    k_cvt8<<<96, 256, 0, stream>>>(Wih1, wi1, G3 * HIDDEN);
    k_swz<<<96, 256, 0, stream>>>(Whh0, wsw0);
    k_swz<<<96, 256, 0, stream>>>(Whh1, wsw1);

    // layer 0: gx0 = x*Wih0^T + bih0 (A staged f32->f16); rec -> h0 (f16)
    k_gemm<float><<<dim3(G3 / 128, N_NODES / 128), 256, 0, stream>>>(x, wi0, bih0, gxbuf, N_NODES, G3, IN_DIM);
    k_rec<<<NGRAPH, 1024, 0, stream>>>(gxbuf, wsw0, bhh0, starts, h0, (float*)nullptr);
    // layer 1: gx1 = h0*Wih1^T + bih1 (f16 MFMA); rec + masked mean -> out (f32)
    k_gemm<_Float16><<<dim3(G3 / 128, N_NODES / 128), 256, 0, stream>>>((const _Float16*)h0, wi1, bih1, gxbuf, N_NODES, G3, HIDDEN);
    k_rec<<<NGRAPH, 1024, 0, stream>>>(gxbuf, wsw1, bhh1, starts, (u16*)nullptr, out);
}

// Round 9
// 1546.996 us; speedup vs baseline: 1.6639x; 1.0010x over previous
//
#include <hip/hip_runtime.h>
#include <hip/hip_bf16.h>

typedef _Float16 half2_t __attribute__((ext_vector_type(2)));
typedef _Float16 f16x8   __attribute__((ext_vector_type(8)));
typedef float    f32x4   __attribute__((ext_vector_type(4)));
typedef unsigned short u16;
typedef unsigned int   u32;

#define N_NODES 65536
#define IN_DIM  256
#define HIDDEN  256
#define G3      768     // 3*HIDDEN gate rows
#define NGRAPH  128

__device__ __forceinline__ float sigf(float x)    { return 1.f / (1.f + __expf(-x)); }
__device__ __forceinline__ float tanhfast(float x){ return 2.f / (1.f + __expf(-2.f * x)) - 1.f; }

// ---- per-graph starts via binary search on sorted batch (int32/int64 autodetect) ----
__global__ void k_starts(const int* __restrict__ batch, int* __restrict__ starts, int n, int ngraph) {
    int g = blockIdx.x * blockDim.x + threadIdx.x;
    if (g > ngraph) return;
    int stride = (batch[n - 1] == 0) ? 2 : 1;
    if (g == ngraph) { starts[g] = n; return; }
    int lo = 0, hi = n;
    while (lo < hi) { int mid = (lo + hi) >> 1; if (batch[(size_t)mid * stride] < g) lo = mid + 1; else hi = mid; }
    starts[g] = lo;
}

// ---- f32 -> f16 elementwise (n multiple of 8) ----
__global__ void k_cvt8(const float* __restrict__ s, u16* __restrict__ d, int n) {
    int t = blockIdx.x * 256 + threadIdx.x;
    int i = t * 8;
    if (i >= n) return;
    float4 a = ((const float4*)(s + i))[0];
    float4 b = ((const float4*)(s + i))[1];
    f16x8 o;
    o[0] = (_Float16)a.x; o[1] = (_Float16)a.y; o[2] = (_Float16)a.z; o[3] = (_Float16)a.w;
    o[4] = (_Float16)b.x; o[5] = (_Float16)b.y; o[6] = (_Float16)b.z; o[7] = (_Float16)b.w;
    *(f16x8*)(d + i) = o;
}

// ---- W_hh f32 [768][256] -> swizzled f16 chunks for k_rec's 1024-thread layout.
// chunk c = ((wv*3 + rg)*8 + i)*64 + l  (wv = wave 0..15, rg = gate 0..2,
// i = k-chunk 0..7, l = lane). Holds
// W_hh[rg*256 + (wv&3)*64 + l][(wv>>2)*64 + 8i .. +7] as 8 f16 (one uint4).
__global__ void k_swz(const float* __restrict__ W, uint4* __restrict__ out) {
    int t = blockIdx.x * 256 + threadIdx.x;
    if (t >= 24576) return;
    int l = t & 63, i = (t >> 6) & 7, rest = t >> 9;  // rest = wv*3+rg, 0..47
    int wv = rest / 3, rg = rest % 3;
    int row = rg * 256 + (wv & 3) * 64 + l;
    int col = (wv >> 2) * 64 + i * 8;
    const float* s = W + row * 256 + col;
    f16x8 o;
#pragma unroll
    for (int q = 0; q < 8; q++) o[q] = (_Float16)s[q];
    out[t] = __builtin_bit_cast(uint4, o);
}

// ---- GEMM: C[M][N] f16 = A[M][K] * B[N][K]^T + bias[N]
// A is f32 (converted during LDS staging) or f16. 128x128 tile per 256-thread
// WG, 4 waves each 64x64 (4x4 of 16x16x32 f16 MFMA).
template <typename AT>
__global__ __launch_bounds__(256) void k_gemm(
    const AT* __restrict__ A, const u16* __restrict__ Bm,
    const float* __restrict__ bias, u16* __restrict__ C,
    int M, int N, int K)
{
    __shared__ u16 As[128 * 40];   // 32 k + 8 pad per row (80B stride, 16B aligned)
    __shared__ u16 Bs[128 * 40];
    const int m0 = blockIdx.y * 128, n0 = blockIdx.x * 128;
    const int t = threadIdx.x;
    const int wave = t >> 6, lane = t & 63;
    const int wm = wave & 1, wn = wave >> 1;
    const int lr = lane & 15, lq = lane >> 4;
    f32x4 acc[4][4] = {};
    const int sr = t >> 1, sp = t & 1;  // staging: 2 threads per row, 16 elems each
    const AT*  gA = A  + (size_t)(m0 + sr) * K + sp * 16;
    const u16* gB = Bm + (size_t)(n0 + sr) * K + sp * 16;
    u16* sA = As + sr * 40 + sp * 16;
    u16* sB = Bs + sr * 40 + sp * 16;
    for (int kt = 0; kt < K; kt += 32) {
        uint4 av0, av1;
        if constexpr (sizeof(AT) == 4) {       // f32 A: load 16 floats, cvt to f16
            float4 a0 = ((const float4*)gA)[0], a1 = ((const float4*)gA)[1];
            float4 a2 = ((const float4*)gA)[2], a3 = ((const float4*)gA)[3];
            f16x8 lo, hi;
            lo[0]=(_Float16)a0.x; lo[1]=(_Float16)a0.y; lo[2]=(_Float16)a0.z; lo[3]=(_Float16)a0.w;
            lo[4]=(_Float16)a1.x; lo[5]=(_Float16)a1.y; lo[6]=(_Float16)a1.z; lo[7]=(_Float16)a1.w;
            hi[0]=(_Float16)a2.x; hi[1]=(_Float16)a2.y; hi[2]=(_Float16)a2.z; hi[3]=(_Float16)a2.w;
            hi[4]=(_Float16)a3.x; hi[5]=(_Float16)a3.y; hi[6]=(_Float16)a3.z; hi[7]=(_Float16)a3.w;
            av0 = __builtin_bit_cast(uint4, lo);
            av1 = __builtin_bit_cast(uint4, hi);
        } else {                               // f16 A: straight 32B
            av0 = ((const uint4*)gA)[0];
            av1 = ((const uint4*)gA)[1];
        }
        uint4 b0 = ((const uint4*)gB)[0], b1 = ((const uint4*)gB)[1];
        gA += 32; gB += 32;
        __syncthreads();
        ((uint4*)sA)[0] = av0; ((uint4*)sA)[1] = av1;
        ((uint4*)sB)[0] = b0;  ((uint4*)sB)[1] = b1;
        __syncthreads();
        f16x8 af[4], bf[4];
#pragma unroll
        for (int i = 0; i < 4; i++)
            af[i] = *(const f16x8*)(As + (wm * 64 + i * 16 + lr) * 40 + lq * 8);
#pragma unroll
        for (int j = 0; j < 4; j++)
            bf[j] = *(const f16x8*)(Bs + (wn * 64 + j * 16 + lr) * 40 + lq * 8);
#pragma unroll
        for (int i = 0; i < 4; i++)
#pragma unroll
            for (int j = 0; j < 4; j++)
                acc[i][j] = __builtin_amdgcn_mfma_f32_16x16x32_f16(af[i], bf[j], acc[i][j], 0, 0, 0);
    }
#pragma unroll
    for (int i = 0; i < 4; i++) {
        int row = m0 + wm * 64 + i * 16 + lq * 4;
#pragma unroll
        for (int j = 0; j < 4; j++) {
            int col = n0 + wn * 64 + j * 16 + lr;
            float bv = bias[col];
#pragma unroll
            for (int rr = 0; rr < 4; rr++) {
                _Float16 v = (_Float16)(acc[i][j][rr] + bv);
                C[(size_t)(row + rr) * N + col] = __builtin_bit_cast(u16, v);
            }
        }
    }
}

// ---- GRU recurrence: one 1024-thread WG per graph. Thread (q=tid>>8, h=tid&255)
// owns k-quarter q of W_hh rows {h, h+256, h+512} = 24 uint4 = 96 VGPRs.
// amdgpu_waves_per_eu(4,4) pins the scheduler's occupancy target to exactly
// 4 waves/EU (= this one WG), giving a 128-reg budget. Without the max bound
// the scheduler targeted 8 waves/EU and throttled to 64 VGPRs, sinking the
// weight loads to L2 every step (R8: 1.19us/step = 49MB/step / 34.5TB/s L2).
__global__ __launch_bounds__(1024) __attribute__((amdgpu_waves_per_eu(4, 4)))
void k_rec(
    const u16* __restrict__ gx,          // [N_NODES][768] f16 input gates (incl. b_ih)
    const uint4* __restrict__ wsw,       // swizzled f16 W_hh (k_swz layout)
    const float* __restrict__ bhh,       // [768] f32
    const int*   __restrict__ starts,    // [129]
    u16* __restrict__ hout,              // f16 h [N_NODES][256] (layer 0) or null
    float* __restrict__ out)             // [128][256] f32 mean (layer 1) or null
{
    __shared__ float part[3][4][HIDDEN]; // [gate][quarter][h]; slot q=0 holds bhh
    __shared__ uint4 hpk4[HIDDEN / 8];   // h packed as 256 f16 (32 uint4)
    const int g = blockIdx.x;
    const int tid = threadIdx.x;
    const int h = tid & 255;
    const int q = tid >> 8;
    const int wv = tid >> 6, l = tid & 63;
    const int start = starts[g];
    const int len = starts[g + 1] - start;
    // register-resident quarter-rows (coalesced fill thanks to swizzle)
    uint4 w[3][8];
#pragma unroll
    for (int rg = 0; rg < 3; rg++)
#pragma unroll
        for (int i = 0; i < 8; i++)
            w[rg][i] = wsw[(size_t)(((wv * 3 + rg) * 8 + i) * 64 + l)];
    if (tid < G3) part[tid >> 8][0][tid & 255] = bhh[tid];  // bias into slot 0
    if (tid < HIDDEN / 8) hpk4[tid] = make_uint4(0, 0, 0, 0);
    float hp = 0.f, hs = 0.f;
    const _Float16* gxr = (const _Float16*)gx + (size_t)start * G3 + h;
    u16* hrow = hout ? (hout + (size_t)start * HIDDEN + h) : (u16*)nullptr;
    float gr = 0.f, gz = 0.f, gn = 0.f;
    if (q == 0 && len > 0) { gr = (float)gxr[0]; gz = (float)gxr[256]; gn = (float)gxr[512]; }
    const int qb = q * 8;
    __syncthreads();
    for (int t = 0; t < len; ++t) {
        float pr = 0.f, pz = 0.f, pn = 0.f;
        if (q == 0) {                              // prefetch next step's gx
            int tn = t + 1 < len ? t + 1 : len - 1;
            size_t o1 = (size_t)tn * G3;
            pr = (float)gxr[o1]; pz = (float)gxr[o1 + 256]; pn = (float)gxr[o1 + 512];
        }
        float ar = 0.f, az = 0.f, an = 0.f;
#pragma unroll
        for (int i = 0; i < 8; i++) {
            uint4 hv = hpk4[qb + i];               // wave-uniform broadcast b128
            half2_t hx = __builtin_bit_cast(half2_t, hv.x), hy = __builtin_bit_cast(half2_t, hv.y);
            half2_t hz2 = __builtin_bit_cast(half2_t, hv.z), hw = __builtin_bit_cast(half2_t, hv.w);
            // gate-interleaved: dependent same-acc ops 3 insts apart (covers fdot2 latency)
            ar = __builtin_amdgcn_fdot2(__builtin_bit_cast(half2_t, w[0][i].x), hx, ar, false);
            az = __builtin_amdgcn_fdot2(__builtin_bit_cast(half2_t, w[1][i].x), hx, az, false);
            an = __builtin_amdgcn_fdot2(__builtin_bit_cast(half2_t, w[2][i].x), hx, an, false);
            ar = __builtin_amdgcn_fdot2(__builtin_bit_cast(half2_t, w[0][i].y), hy, ar, false);
            az = __builtin_amdgcn_fdot2(__builtin_bit_cast(half2_t, w[1][i].y), hy, az, false);
            an = __builtin_amdgcn_fdot2(__builtin_bit_cast(half2_t, w[2][i].y), hy, an, false);
            ar = __builtin_amdgcn_fdot2(__builtin_bit_cast(half2_t, w[0][i].z), hz2, ar, false);
            az = __builtin_amdgcn_fdot2(__builtin_bit_cast(half2_t, w[1][i].z), hz2, az, false);
            an = __builtin_amdgcn_fdot2(__builtin_bit_cast(half2_t, w[2][i].z), hz2, an, false);
            ar = __builtin_amdgcn_fdot2(__builtin_bit_cast(half2_t, w[0][i].w), hw, ar, false);
            az = __builtin_amdgcn_fdot2(__builtin_bit_cast(half2_t, w[1][i].w), hw, az, false);
            an = __builtin_amdgcn_fdot2(__builtin_bit_cast(half2_t, w[2][i].w), hw, an, false);
        }
        if (q) { part[0][q][h] = ar; part[1][q][h] = az; part[2][q][h] = an; }
        __syncthreads();
        if (!q) {
            float sr = ar + part[0][0][h] + part[0][1][h] + part[0][2][h] + part[0][3][h];
            float sz = az + part[1][0][h] + part[1][1][h] + part[1][2][h] + part[1][3][h];
            float sn = an + part[2][0][h] + part[2][1][h] + part[2][2][h] + part[2][3][h];
            float r = sigf(gr + sr);
            float z = sigf(gz + sz);
            float n = tanhfast(gn + r * sn);       // sn includes bhh_n (inside r*)
            float hnew = (1.f - z) * n + z * hp;
            hp = hnew; hs += hnew;
            _Float16 ph = (_Float16)hnew;
            u16 pk = __builtin_bit_cast(u16, ph);
            ((u16*)hpk4)[h] = pk;
            if (hrow) hrow[(size_t)t * HIDDEN] = pk;
            gr = pr; gz = pz; gn = pn;
        }
        __syncthreads();
    }
    if (out && !q) {
        float inv = 1.f / (float)(len > 0 ? len : 1);
        out[g * HIDDEN + h] = hs * inv;            // f32 output
    }
}

extern "C" void kernel_launch(void* const* d_in, const int* in_sizes, int n_in,
                              void* d_out, int out_size, void* d_ws, size_t ws_size,
                              hipStream_t stream)
{
    const float* x     = (const float*)d_in[0];
    const int*   batch = (const int*)d_in[1];
    const float* Wih0  = (const float*)d_in[2];
    const float* Whh0  = (const float*)d_in[3];
    const float* bih0  = (const float*)d_in[4];
    const float* bhh0  = (const float*)d_in[5];
    const float* Wih1  = (const float*)d_in[6];
    const float* Whh1  = (const float*)d_in[7];
    const float* bih1  = (const float*)d_in[8];
    const float* bhh1  = (const float*)d_in[9];
    float* out = (float*)d_out;

    // Workspace ~135.5 MB
    char* ws = (char*)d_ws;
    size_t o = 0;
    int*   starts = (int*)  (ws + o); o += 4096;
    u16*   wi0    = (u16*)  (ws + o); o += (size_t)G3 * IN_DIM * 2;      // 384 KB (f16 W_ih0)
    u16*   wi1    = (u16*)  (ws + o); o += (size_t)G3 * HIDDEN * 2;     // 384 KB (f16 W_ih1)
    uint4* wsw0   = (uint4*)(ws + o); o += (size_t)G3 * HIDDEN * 2;     // 384 KB
    uint4* wsw1   = (uint4*)(ws + o); o += (size_t)G3 * HIDDEN * 2;     // 384 KB
    u16*   h0     = (u16*)  (ws + o); o += (size_t)N_NODES * HIDDEN * 2; // 33.5 MB (f16)
    u16*   gxbuf  = (u16*)  (ws + o); o += (size_t)N_NODES * G3 * 2;     // 100.7 MB (f16, reused)

    k_starts<<<1, 256, 0, stream>>>(batch, starts, N_NODES, NGRAPH);
    k_cvt8<<<96, 256, 0, stream>>>(Wih0, wi0, G3 * IN_DIM);
    k_cvt8<<<96, 256, 0, stream>>>(Wih1, wi1, G3 * HIDDEN);
    k_swz<<<96, 256, 0, stream>>>(Whh0, wsw0);
    k_swz<<<96, 256, 0, stream>>>(Whh1, wsw1);

    // layer 0: gx0 = x*Wih0^T + bih0 (A staged f32->f16); rec -> h0 (f16)
    k_gemm<float><<<dim3(G3 / 128, N_NODES / 128), 256, 0, stream>>>(x, wi0, bih0, gxbuf, N_NODES, G3, IN_DIM);
    k_rec<<<NGRAPH, 1024, 0, stream>>>(gxbuf, wsw0, bhh0, starts, h0, (float*)nullptr);
    // layer 1: gx1 = h0*Wih1^T + bih1 (f16 MFMA); rec + masked mean -> out (f32)
    k_gemm<_Float16><<<dim3(G3 / 128, N_NODES / 128), 256, 0, stream>>>((const _Float16*)h0, wi1, bih1, gxbuf, N_NODES, G3, HIDDEN);
    k_rec<<<NGRAPH, 1024, 0, stream>>>(gxbuf, wsw1, bhh1, starts, (u16*)nullptr, out);
}